// Round 9
// baseline (145.178 us; speedup 1.0000x reference)
//
#include <hip/hip_runtime.h>
#include <math.h>

typedef unsigned int u32;
typedef unsigned short u16;
typedef unsigned char u8;
typedef int i32x4 __attribute__((ext_vector_type(4)));
typedef int i32x16 __attribute__((ext_vector_type(16)));

#if __has_builtin(__builtin_amdgcn_mfma_i32_32x32x32_i8)
#define HAS_MFMA_I8 1
#else
#define HAS_MFMA_I8 0
#endif

__device__ __forceinline__ u32 sad8(u32 a, u32 b, u32 c){
#if __has_builtin(__builtin_amdgcn_sad_u8)
    return __builtin_amdgcn_sad_u8(a, b, c);
#else
    u32 s = c;
#pragma unroll
    for (int k = 0; k < 4; ++k){
        int av = (int)((a >> (8*k)) & 255u), bv = (int)((b >> (8*k)) & 255u);
        s += (u32)(av > bv ? av - bv : bv - av);
    }
    return s;
#endif
}

__device__ __forceinline__ u32 hsum16(u32 x, u32 c){ return c + (x & 0xFFFFu) + (x >> 16); }

__device__ __forceinline__ int sdot4(u32 a, u32 b, int c){
#if __has_builtin(__builtin_amdgcn_sdot4)
    return __builtin_amdgcn_sdot4((int)a, (int)b, c, false);
#else
    int s = c;
#pragma unroll
    for (int k = 0; k < 4; ++k){
        int av = (int)(signed char)((a >> (8*k)) & 255u);
        int bv = (int)(signed char)((b >> (8*k)) & 255u);
        s += av * bv;
    }
    return s;
#endif
}

// ---- R18: SINGLE dispatch, no grid-sync, no redundant quant.
// R17 diagnostic: healthy fused F ~= 6.5us (at structural floor); the
// controllable cost is ~23us of dispatch boundaries + prep (3h + prep,
// h ~= 6-8us/boundary) on top of the fixed 41.5us workspace poison fill.
// Design (the three prior fusion failures each addressed):
//  - vs R12 (+14us redundant quant): each block quantizes ONLY its 4 rows
//    [4bid,4bid+4) into global q8, publishes with __threadfence() + two
//    per-block MAGIC flag words (device-scope atomics; Guideline 16).
//    Consumers bounded-poll the 24 owner flags of their tile (48 iters),
//    then one acquire __threadfence() and vector-load q8 rows.
//  - vs R14 (coop codegen broke regalloc): plain <<<512,512>>> launch.
//  - vs deadlock/co-residency risk: polls are BOUNDED; on timeout the lane
//    quantizes its 16-byte row segment directly from z/zpr into LDS —
//    bit-identical values — so correctness never depends on scheduling.
//  - Dual distinct magics: a single-dword poison pattern P would need
//    P==MAGA^bid AND P==MAGB^bid simultaneously -> impossible (MAGA!=MAGB).
//    Workspace re-poison each iteration resets flags (required & verified:
//    fill covers all 256MiB).
//  - norms computed in-block from staged LDS by waves 4-7 (sdot4(x,x),
//    exact ints < 2^24), overlapping waves 0-3's MFMA -> no cross-block
//    dependency on norms at all.
// Sad loop / MFMA / epilogue / output are R15-verbatim (proven absmax 4.0).
// LDS: staging 15360 w + nfin[96] + rdy[32] = 15488 w = 61.95KB, 2 blk/CU.
#define RS 20
#define L1S 520
#define MAGA 0x51AD0001u
#define MAGB 0xB02F5EEDu
#define POLLS 48
__global__ __launch_bounds__(512)
__attribute__((amdgpu_waves_per_eu(4, 4)))
void fused_single(const float* __restrict__ z,
                  const float* __restrict__ zpr,
                  float* __restrict__ out,
                  u8* __restrict__ q8,
                  u32* __restrict__ flags){
    __shared__ u32 smem[15488];
    const int t = threadIdx.x;
    const int lane = t & 63;
    const int w = t >> 6;
    const int bid = blockIdx.x;
    const int bn = bid & 31;
    const int bm = bid >> 5;
    const int n_base = bn*32, m_base = bm*64;
    float* nfin = (float*)(smem + 15360);   // [96]
    u32*   rdy  = smem + 15456;             // [24 used]

    // ---- phase 1: quantize owned rows [4bid, 4bid+4) -> global q8 ----
    {
        const int row  = bid*4 + (w >> 1);
        const int half = w & 1;
        const float* src = (row < 1024) ? (z + (size_t)row*512)
                                        : (zpr + (size_t)(row - 1024)*512);
        float4 f = ((const float4*)(src + half*256))[lane];
        u32 q0 = (u32)fmaf(f.x, 16.f, 128.5f) & 255u;
        u32 q1 = (u32)fmaf(f.y, 16.f, 128.5f) & 255u;
        u32 q2 = (u32)fmaf(f.z, 16.f, 128.5f) & 255u;
        u32 q3 = (u32)fmaf(f.w, 16.f, 128.5f) & 255u;
        ((u32*)(q8 + (size_t)row*512 + half*256))[lane] = q0 | (q1<<8) | (q2<<16) | (q3<<24);
    }
    __syncthreads();                 // all 8 waves' q8 stores issued & drained
    if (t < 2){
        __threadfence();             // release: write back L2 before publish
        atomicExch(&flags[2*bid + t], (t == 0 ? MAGA : MAGB) ^ (u32)bid);
    }
    // ---- poll the 24 owner blocks this tile needs (bounded; no deadlock) ----
    if (t < 24){
        const int owner = (t < 8) ? (bn*8 + t) : (256 + bm*16 + (t - 8));
        const u32 ea = MAGA ^ (u32)owner, eb = MAGB ^ (u32)owner;
        u32 ok = 0;
        for (int it = 0; it < POLLS && !ok; ++it){
            u32 a = atomicCAS(&flags[2*owner],     0u, 0u);
            u32 b = atomicCAS(&flags[2*owner + 1], 0u, 0u);
            ok = (u32)((a == ea) && (b == eb));
        }
        rdy[t] = ok;
    }
    __syncthreads();
    __threadfence();                 // acquire: invalidate caches before q8 reads

    // ---- stage: wave w's k-slice [64w,64w+64), 96 rows; fast (q8) or
    // fallback (quantize from f32 -> bit-identical) per row ----
    u32* wbase = smem + w*1920;
    {
        const int c = lane & 3;
        const int r4 = lane >> 2;
#pragma unroll
        for (int j = 0; j < 6; ++j){
            const int rt = j*16 + r4;        // 0..95
            const bool zr = rt < 32;
            const int grow = zr ? (n_base + rt) : (1024 + m_base + rt - 32);
            const int oidx = zr ? (rt >> 2) : (8 + ((rt - 32) >> 2));
            uint4 v;
            if (rdy[oidx]){
                v = *(const uint4*)(q8 + (size_t)grow*512 + 64*w + 16*c);
            } else {
                const float* fs = (zr ? (z + (size_t)grow*512)
                                      : (zpr + (size_t)(grow - 1024)*512)) + 64*w + 16*c;
                u32 bw[4];
#pragma unroll
                for (int q = 0; q < 4; ++q){
                    float4 f = ((const float4*)fs)[q];
                    u32 a0 = (u32)fmaf(f.x, 16.f, 128.5f) & 255u;
                    u32 a1 = (u32)fmaf(f.y, 16.f, 128.5f) & 255u;
                    u32 a2 = (u32)fmaf(f.z, 16.f, 128.5f) & 255u;
                    u32 a3 = (u32)fmaf(f.w, 16.f, 128.5f) & 255u;
                    bw[q] = a0 | (a1<<8) | (a2<<16) | (a3<<24);
                }
                v = make_uint4(bw[0], bw[1], bw[2], bw[3]);
            }
            *(uint4*)(wbase + rt*RS + 4*c) = v;
        }
    }

    const int tn = lane & 3, tm = lane >> 2;
    u32 acc[8][4];
#pragma unroll
    for (int i = 0; i < 8; ++i)
#pragma unroll
        for (int j = 0; j < 4; ++j) acc[i][j] = 0u;

#if !HAS_MFMA_I8
    int dpa[8][4];
#pragma unroll
    for (int i = 0; i < 8; ++i)
#pragma unroll
        for (int j = 0; j < 4; ++j) dpa[i][j] = 0;
#endif

    // ---- sad hot loop (R15 verbatim): wave-local, 2-deep SW pipeline ----
    {
        uint4 av[2][4], bv[2][4];
#pragma unroll
        for (int j2 = 0; j2 < 4; ++j2)
            bv[0][j2] = *(const uint4*)(wbase + (32 + tm + 16*j2)*RS);
#pragma unroll
        for (int i = 0; i < 4; ++i)
            av[0][i] = *(const uint4*)(wbase + (tn + 4*i)*RS);

#pragma unroll
        for (int s = 0; s < 8; ++s){
            const int c   = s >> 1, ih = s & 1;
            const int cur = s & 1,  nxt = cur ^ 1;
            const int bcur = c & 1;
            if (s < 7){
                const int s1 = s + 1;
                const int c1 = s1 >> 1, ih1 = s1 & 1;
#pragma unroll
                for (int i = 0; i < 4; ++i)
                    av[nxt][i] = *(const uint4*)(wbase + (tn + 4*(4*ih1 + i))*RS + 4*c1);
                if (ih1 == 0){
#pragma unroll
                    for (int j2 = 0; j2 < 4; ++j2)
                        bv[c1 & 1][j2] = *(const uint4*)(wbase + (32 + tm + 16*j2)*RS + 4*c1);
                }
            }
#pragma unroll
            for (int i = 0; i < 4; ++i)
#pragma unroll
                for (int j2 = 0; j2 < 4; ++j2){
                    u32 sa = acc[4*ih + i][j2];
                    sa = sad8(av[cur][i].x, bv[bcur][j2].x, sa);
                    sa = sad8(av[cur][i].y, bv[bcur][j2].y, sa);
                    sa = sad8(av[cur][i].z, bv[bcur][j2].z, sa);
                    sa = sad8(av[cur][i].w, bv[bcur][j2].w, sa);
                    acc[4*ih + i][j2] = sa;
#if !HAS_MFMA_I8
                    int d = dpa[4*ih + i][j2];
                    d = sdot4(av[cur][i].x^0x80808080u, bv[bcur][j2].x^0x80808080u, d);
                    d = sdot4(av[cur][i].y^0x80808080u, bv[bcur][j2].y^0x80808080u, d);
                    d = sdot4(av[cur][i].z^0x80808080u, bv[bcur][j2].z^0x80808080u, d);
                    d = sdot4(av[cur][i].w^0x80808080u, bv[bcur][j2].w^0x80808080u, d);
                    dpa[4*ih + i][j2] = d;
#endif
                }
        }
    }

    __syncthreads();   // barrier A: all waves' staging complete; region intact

#if HAS_MFMA_I8
    // ---- dp via i8 MFMA: waves 0-3 read all waves' staged slices ----
    i32x16 dpacc = (i32x16)(0);
    const int mt = w & 1;
    const int kh = w >> 1;
    const int arow = lane & 31;
    const int brow = 32 + mt*32 + (lane & 31);
    const int o1 = lane >> 5;
    if (w < 4){
#pragma unroll
        for (int s = 0; s < 4; ++s){
            const u32* gb = smem + (kh*4 + s)*1920;
#pragma unroll
            for (int h = 0; h < 2; ++h){
                uint4 a = *(const uint4*)(gb + arow*RS + 8*h + 4*o1);
                uint4 b = *(const uint4*)(gb + brow*RS + 8*h + 4*o1);
                uint4 ax = make_uint4(a.x^0x80808080u, a.y^0x80808080u, a.z^0x80808080u, a.w^0x80808080u);
                uint4 bx = make_uint4(b.x^0x80808080u, b.y^0x80808080u, b.z^0x80808080u, b.w^0x80808080u);
                dpacc = __builtin_amdgcn_mfma_i32_32x32x32_i8(__builtin_bit_cast(i32x4, ax),
                                                              __builtin_bit_cast(i32x4, bx),
                                                              dpacc, 0, 0, 0);
            }
        }
    }
#endif

    // ---- norms from staged LDS: waves 4-7 (overlaps MFMA), exact ints ----
    if (w >= 4){
        const int idx = t - 256;         // 0..255
        const int r = idx >> 1;          // 0..127, valid < 96
        const int part = idx & 1;        // half of the 128 words of row r
        if (r < 96){
            int ssq = 0;
#pragma unroll
            for (int sl = 0; sl < 4; ++sl){
                const u32* p = smem + (size_t)(part*4 + sl)*1920 + r*RS;
#pragma unroll
                for (int q = 0; q < 4; ++q){
                    uint4 u = *(const uint4*)(p + 4*q);
                    u32 x0 = u.x^0x80808080u, x1 = u.y^0x80808080u;
                    u32 x2 = u.z^0x80808080u, x3 = u.w^0x80808080u;
                    ssq = sdot4(x0, x0, ssq); ssq = sdot4(x1, x1, ssq);
                    ssq = sdot4(x2, x2, ssq); ssq = sdot4(x3, x3, ssq);
                }
            }
            ssq += __shfl_xor(ssq, 1);
            if (part == 0) nfin[r] = (float)ssq;
        }
    }

    __syncthreads();   // barrier B: all staging reads done; region now dead

    // ---- epilogue (overlays staging; nfin above it survives) ----
    u16*   l1b  = (u16*)smem;                  // [32 n][520] u16
    float* dpbA = (float*)(smem + 8320);       // [32][65]
    float* dpbB = (float*)(smem + 10400);      // [32][65]

#pragma unroll
    for (int i = 0; i < 8; ++i)
#pragma unroll
        for (int j = 0; j < 4; ++j)
            l1b[(tn + 4*i)*L1S + (tm + 16*j)*8 + w] = (u16)acc[i][j];

#if HAS_MFMA_I8
    if (w < 4){
        float* dpb = kh ? dpbB : dpbA;
        const int mcol = mt*32 + (lane & 31);
#pragma unroll
        for (int reg = 0; reg < 16; ++reg){
            const int n = (reg & 3) + 8*(reg >> 2) + 4*(lane >> 5);
            dpb[n*65 + mcol] = (float)dpacc[reg];
        }
    }
#endif
    __syncthreads();   // barrier C

    const int m  = t >> 3;
    const int n0 = 4*(t & 7);
    float4 nz4 = *(const float4*)&nfin[n0];
    const float np = nfin[32 + m];
    const float nzv[4] = {nz4.x, nz4.y, nz4.z, nz4.w};

    float l1q[4], dpq[4];
#pragma unroll
    for (int i = 0; i < 4; ++i){
        const int n = n0 + i;
        uint4 lp = *(const uint4*)&l1b[n*L1S + m*8];
        u32 s = hsum16(lp.x, 0u); s = hsum16(lp.y, s);
        s = hsum16(lp.z, s);      s = hsum16(lp.w, s);
        l1q[i] = (float)s;
#if HAS_MFMA_I8
        dpq[i] = dpbA[n*65 + m] + dpbB[n*65 + m];
#else
        dpq[i] = 0.f;
#endif
    }

#if !HAS_MFMA_I8
    {
        float* dpf = (float*)(smem + 8320);   // [2048][2]
#pragma unroll
        for (int ph = 0; ph < 4; ++ph){
            __syncthreads();
            if ((w >> 1) == ph){
#pragma unroll
                for (int i = 0; i < 8; ++i)
#pragma unroll
                    for (int j = 0; j < 4; ++j)
                        dpf[((tn + 4*i)*64 + tm + 16*j)*2 + (w & 1)] = (float)dpa[i][j];
            }
            __syncthreads();
#pragma unroll
            for (int i = 0; i < 4; ++i){
                const int cell = (n0 + i)*64 + m;
                dpq[i] += dpf[cell*2] + dpf[cell*2 + 1];
            }
        }
    }
#endif

    float ov[12];
#pragma unroll
    for (int i = 0; i < 4; ++i){
        const float l2q = nzv[i] + np - 2.f*dpq[i];
        ov[3*i]     = l1q[i] * 0.0625f;
        ov[3*i + 1] = sqrtf(fmaxf(l2q, 0.f)) * 0.0625f;
        ov[3*i + 2] = dpq[i] * 0.00390625f;
    }
    float4* op = (float4*)(out + (((size_t)(m_base + m))*1024 + n_base + n0)*3);
    op[0] = make_float4(ov[0], ov[1], ov[2],  ov[3]);
    op[1] = make_float4(ov[4], ov[5], ov[6],  ov[7]);
    op[2] = make_float4(ov[8], ov[9], ov[10], ov[11]);
}

extern "C" void kernel_launch(void* const* d_in, const int* in_sizes, int n_in,
                              void* d_out, int out_size, void* d_ws, size_t ws_size,
                              hipStream_t stream) {
    const float* z   = (const float*)d_in[0];
    const float* zpr = (const float*)d_in[1];
    float* out = (float*)d_out;
    u8*  q8    = (u8*)d_ws;                            // 1 MB
    u32* flags = (u32*)((char*)d_ws + (1 << 20));      // 4 KB (re-poisoned each iter)

    fused_single<<<512, 512, 0, stream>>>(z, zpr, out, q8, flags);
}